// Round 2
// baseline (357.162 us; speedup 1.0000x reference)
//
#include <hip/hip_runtime.h>
#include <stdint.h>

// ---------- common helpers ----------
typedef __attribute__((ext_vector_type(8))) short bf16x8;   // 8 bf16 (4 VGPRs)
typedef __attribute__((ext_vector_type(4))) float f32x4;    // MFMA accumulator

#define AS1 __attribute__((address_space(1)))
#define AS3 __attribute__((address_space(3)))

// async global->LDS, 16B per lane; LDS dest = wave-uniform base + lane*16.
__device__ __forceinline__ void gl2lds16(const void* g, void* l) {
    __builtin_amdgcn_global_load_lds((const AS1 void*)g, (AS3 void*)l, 16, 0, 0);
}

__device__ __forceinline__ unsigned short f2bf(float f) {
    uint32_t u = __builtin_bit_cast(uint32_t, f);
    uint32_t r = (u + 0x7fffu + ((u >> 16) & 1u)) >> 16;    // RNE
    return (unsigned short)r;
}

// ---------- problem constants ----------
// B=4, S=4096, H=512
constexpr int S = 4096;
constexpr int H = 512;
constexpr size_t OFF_XB  = 0;                         // x  bf16   [4*4096*512]
constexpr size_t OFF_SB  = 16777216;                  // x+rp bf16 (contiguous after xb)
constexpr size_t OFF_WQB = 33554432;                  // Wq bf16 [512*512]
constexpr size_t OFF_WKB = 34078720;                  // Wk bf16 (contiguous after Wq)
constexpr size_t OFF_WVB = 34603008;
constexpr size_t OFF_BQK = 35127296;                  // fp32 [2][512]: row0=bq, row1=2*bk
constexpr size_t OFF_QB  = 35131392;                  // Q bf16 [4][4096][512]
constexpr size_t OFF_K2B = OFF_QB  + 16777216;        // K+Kr bf16 (contiguous after Q)
constexpr size_t OFF_VTB = OFF_K2B + 16777216;        // V^T bf16 [4][512][4096]
constexpr size_t OFF_PB  = OFF_VTB + 16777216;        // P = exp(scores) bf16 [4][4096][4096]
constexpr size_t OFF_L   = OFF_PB  + 134217728;       // row sums fp32 [4][4096]

// ---------- fused prep: casts, x+rp fusion, bias prep, lrow zero ----------
__global__ __launch_bounds__(256) void prep_all(const float* __restrict__ x,
                                                const float* __restrict__ rp,
                                                const float* __restrict__ wq,
                                                const float* __restrict__ wk,
                                                const float* __restrict__ wv,
                                                const float* __restrict__ bq,
                                                const float* __restrict__ bk,
                                                unsigned short* __restrict__ xb,
                                                unsigned short* __restrict__ sb,
                                                unsigned short* __restrict__ wqb,
                                                unsigned short* __restrict__ wkb,
                                                unsigned short* __restrict__ wvb,
                                                float* __restrict__ bqk,
                                                float* __restrict__ lrow) {
    if (blockIdx.x < 8192) {
        const int i = (blockIdx.x * 256 + threadIdx.x) * 4;
        float4 xv = *(const float4*)(x + i);
        float4 rv = *(const float4*)(rp + i);
        uint2 xo, so;
        xo.x = (uint32_t)f2bf(xv.x) | ((uint32_t)f2bf(xv.y) << 16);
        xo.y = (uint32_t)f2bf(xv.z) | ((uint32_t)f2bf(xv.w) << 16);
        so.x = (uint32_t)f2bf(xv.x + rv.x) | ((uint32_t)f2bf(xv.y + rv.y) << 16);
        so.y = (uint32_t)f2bf(xv.z + rv.z) | ((uint32_t)f2bf(xv.w + rv.w) << 16);
        *(uint2*)(xb + i) = xo;
        *(uint2*)(sb + i) = so;
    } else {
        const int t = (blockIdx.x - 8192) * 256 + threadIdx.x;   // 0..65535
        const int i = t * 4;
        float4 q = *(const float4*)(wq + i);
        float4 k = *(const float4*)(wk + i);
        float4 v = *(const float4*)(wv + i);
        uint2 o;
        o.x = (uint32_t)f2bf(q.x) | ((uint32_t)f2bf(q.y) << 16);
        o.y = (uint32_t)f2bf(q.z) | ((uint32_t)f2bf(q.w) << 16);
        *(uint2*)(wqb + i) = o;
        o.x = (uint32_t)f2bf(k.x) | ((uint32_t)f2bf(k.y) << 16);
        o.y = (uint32_t)f2bf(k.z) | ((uint32_t)f2bf(k.w) << 16);
        *(uint2*)(wkb + i) = o;
        o.x = (uint32_t)f2bf(v.x) | ((uint32_t)f2bf(v.y) << 16);
        o.y = (uint32_t)f2bf(v.z) | ((uint32_t)f2bf(v.w) << 16);
        *(uint2*)(wvb + i) = o;
        if (t < 128) {                                    // row0 = bq
            *(float4*)(bqk + t * 4) = *(const float4*)(bq + t * 4);
        } else if (t < 256) {                             // row1 = 2*bk
            const int u = t - 128;
            float4 b = *(const float4*)(bk + u * 4);
            *(float4*)(bqk + 512 + u * 4) = make_float4(2.f * b.x, 2.f * b.y, 2.f * b.z, 2.f * b.w);
        }
        if (t < 4096) {                                   // lrow[16384] = 0
            *(float4*)(lrow + t * 4) = make_float4(0.f, 0.f, 0.f, 0.f);
        }
    }
}

// ---------- generic bt-form bf16 MFMA GEMM (m97 structure, kept for small GEMMs + PV) ----------
template <int MODE, int SWZ, int NPANEL>
__global__ __launch_bounds__(256, 2)
void gemm_bt(const unsigned short* __restrict__ Abase,
             const unsigned short* __restrict__ Bbase,
             void* __restrict__ Cbase,
             int M, int N, int K,
             long long sAz, long long sBz, long long sCz,
             const float* __restrict__ bias_n, long long sBNz,
             const float* __restrict__ bias_m,
             float scale,
             float* __restrict__ rowdiv, long long sRz)
{
    int bx = blockIdx.x, by = blockIdx.y, bz = blockIdx.z;
    if (SWZ) {
        const int gx = gridDim.x, gy = gridDim.y;
        const int id  = bx + gx * (by + gridDim.y * bz);
        const int xcd = id & 7;
        const int k   = id >> 3;
        const int kg  = k / gx;
        bx = k - kg * gx;
        const int g = xcd + 8 * kg;
        const int gz = g / gy;
        by = g - gz * gy;
        bz = gz;
    }
    const int z = bz;
    const unsigned short* A  = Abase + (size_t)z * (size_t)sAz;
    const unsigned short* Bm = Bbase + (size_t)z * (size_t)sBz;
    const int bn = bx * 128;
    const int bm = by * 128;

    constexpr int STAGE_BYTES = NPANEL * 16384;
    constexpr int SMEM_BYTES = (MODE == 1) ? STAGE_BYTES
                             : (STAGE_BYTES > 34816 ? STAGE_BYTES : 34816);
    __shared__ __align__(16) char smem[SMEM_BYTES];
    unsigned short* As = (unsigned short*)smem;                       // [NPANEL][128][32]
    unsigned short* Bs = (unsigned short*)(smem + NPANEL * 8192);     // [NPANEL][128][32]

    const int tid  = threadIdx.x;
    const int wave = tid >> 6;
    const int lane = tid & 63;
    const int lm   = lane & 15;
    const int quad = lane >> 4;
    const int wm   = (wave >> 1) * 64;
    const int wn   = (wave & 1) * 64;

    const int r0 = tid >> 2;
    const int p0 = tid & 3;

    f32x4 acc[4][4] = {};

    for (int k0 = 0; k0 < K; k0 += 32 * NPANEL) {
        __syncthreads();
        #pragma unroll
        for (int pp = 0; pp < NPANEL; pp++) {
            const unsigned short* Ap = A  + (size_t)(bm + r0) * K + k0 + pp * 32 + p0 * 8;
            const unsigned short* Bp = Bm + (size_t)(bn + r0) * K + k0 + pp * 32 + p0 * 8;
            unsigned short* Asp = As + pp * 4096;
            unsigned short* Bsp = Bs + pp * 4096;
            gl2lds16(Ap,                    Asp + wave * 512);
            gl2lds16(Ap + (size_t)64 * K,   Asp + 2048 + wave * 512);
            gl2lds16(Bp,                    Bsp + wave * 512);
            gl2lds16(Bp + (size_t)64 * K,   Bsp + 2048 + wave * 512);
        }
        __syncthreads();

        #pragma unroll
        for (int pp = 0; pp < NPANEL; pp++) {
            bf16x8 af[4], bfr[4];
            #pragma unroll
            for (int t = 0; t < 4; t++)
                af[t]  = *(const bf16x8*)(As + pp * 4096 + (wm + t * 16 + lm) * 32 + quad * 8);
            #pragma unroll
            for (int t = 0; t < 4; t++)
                bfr[t] = *(const bf16x8*)(Bs + pp * 4096 + (wn + t * 16 + lm) * 32 + quad * 8);
            #pragma unroll
            for (int mt = 0; mt < 4; mt++)
                #pragma unroll
                for (int nt = 0; nt < 4; nt++)
                    acc[mt][nt] = __builtin_amdgcn_mfma_f32_16x16x32_bf16(af[mt], bfr[nt], acc[mt][nt], 0, 0, 0);
        }
    }

    if (MODE == 1) {
        float* C = (float*)Cbase + (size_t)z * (size_t)sCz;
        const float* rd = rowdiv + (size_t)z * (size_t)sRz;
        #pragma unroll
        for (int mt = 0; mt < 4; mt++) {
            #pragma unroll
            for (int i = 0; i < 4; i++) {
                const int row = bm + wm + mt * 16 + quad * 4 + i;
                const float inv = 1.0f / rd[row];
                const size_t rb = (size_t)row * (size_t)N;
                #pragma unroll
                for (int nt = 0; nt < 4; nt++) {
                    const int col = bn + wn + nt * 16 + lm;
                    C[rb + col] = acc[mt][nt][i] * inv;
                }
            }
        }
    } else {
        unsigned short* C = (unsigned short*)Cbase + (size_t)z * (size_t)sCz;
        const float* bn_ptr = (MODE == 0 && bias_n) ? bias_n + (size_t)z * (size_t)sBNz : nullptr;
        float* lr = (MODE == 2) ? rowdiv + (size_t)z * (size_t)sRz : nullptr;
        unsigned short* Ct = (unsigned short*)smem;   // 128 x 136 bf16 tile
        __syncthreads();
        #pragma unroll
        for (int mt = 0; mt < 4; mt++) {
            #pragma unroll
            for (int i = 0; i < 4; i++) {
                const int r = wm + mt * 16 + quad * 4 + i;
                if (MODE == 0) {
                    const float badd = bias_m ? bias_m[bm + r] : 0.0f;
                    #pragma unroll
                    for (int nt = 0; nt < 4; nt++) {
                        const int col = bn + wn + nt * 16 + lm;
                        float v = acc[mt][nt][i] * scale + badd;
                        if (bn_ptr) v += bn_ptr[col];
                        Ct[r * 136 + wn + nt * 16 + lm] = f2bf(v);
                    }
                } else {
                    float rsum = 0.f;
                    #pragma unroll
                    for (int nt = 0; nt < 4; nt++) {
                        float p = __expf(acc[mt][nt][i] * scale);
                        rsum += p;
                        Ct[r * 136 + wn + nt * 16 + lm] = f2bf(p);
                    }
                    rsum += __shfl_xor(rsum, 1);
                    rsum += __shfl_xor(rsum, 2);
                    rsum += __shfl_xor(rsum, 4);
                    rsum += __shfl_xor(rsum, 8);
                    if (lm == 0) atomicAdd(lr + bm + r, rsum);
                }
            }
        }
        __syncthreads();
        #pragma unroll
        for (int j = 0; j < 8; j++) {
            const int r   = (tid >> 4) + 16 * j;
            const int c16 = tid & 15;
            uint4 vv = *(const uint4*)(Ct + r * 136 + c16 * 8);
            *(uint4*)(C + (size_t)(bm + r) * (size_t)N + bn + c16 * 8) = vv;
        }
    }
}

// ---------- 8-phase 256x256 BK=64 score kernel: P = exp(Q@K2^T * scale), lrow += rowsums ----------
// 512 threads = 8 waves (2 row-groups r2 x 4 col-groups c4). Per phase a 128x128
// C-quadrant (hm,hn) is computed by all 8 waves (each 64x32); per-wave acc[2][2][4][2]
// f32x4 = 128 VGPR. LDS 128 KiB STATIC (gfx950 LDS limit 160 KiB; static avoids the
// dynamic-smem hipFuncSetAttribute call, which is unsafe under graph capture).
// T2 swizzle: 16B slot ^= (row&7); staged via pre-swizzled GLOBAL source (linear LDS
// dest, m173/m201) and read with the same XOR -> per-slot bank load is exactly 8
// lanes x 1 dword (optimal). T3+T4: counted vmcnt(4) at p3/p7 ends only (each LDS
// region is staged exactly one phase after its last read; the tile about to be
// consumed is the 8 oldest loads). T5: setprio(1) around each 16-MFMA cluster.
__global__ __launch_bounds__(512, 2)
void qk_exp_8ph(const unsigned short* __restrict__ Qb,
                const unsigned short* __restrict__ K2b,
                unsigned short* __restrict__ Pb,
                float* __restrict__ lrow)
{
    constexpr int N  = 4096;
    constexpr int Kd = 512;
    constexpr float scale = 0.044194173824159216f;
    __shared__ __align__(16) char smem8[131072];

    int bx = blockIdx.x, by = blockIdx.y, bz = blockIdx.z;
    {   // XCD swizzle (nwg = 1024 = 8*128, bijective)
        const int gx = gridDim.x, gy = gridDim.y;
        const int id  = bx + gx * (by + gy * bz);
        const int xcd = id & 7;
        const int k   = id >> 3;
        const int kg  = k / gx;
        bx = k - kg * gx;
        const int g = xcd + 8 * kg;
        const int gz = g / gy;
        by = g - gz * gy;
        bz = gz;
    }
    const int z  = bz;
    const int bm = by * 256;
    const int bn = bx * 256;
    const unsigned short* Az = Qb  + (size_t)z * (size_t)N * Kd;
    const unsigned short* Bz = K2b + (size_t)z * (size_t)N * Kd;

    unsigned short* A0 = (unsigned short*)smem8;       // [256][64] bf16, 32 KB each
    unsigned short* B0 = A0 + 256 * 64;
    unsigned short* A1 = B0 + 256 * 64;
    unsigned short* B1 = A1 + 256 * 64;

    const int tid  = threadIdx.x;
    const int wave = tid >> 6;
    const int lane = tid & 63;
    const int lm   = lane & 15;
    const int quad = lane >> 4;
    const int r2   = wave >> 2;      // 0..1 : 64-row group within quadrant
    const int c4   = wave & 3;       // 0..3 : 32-col group within quadrant

    // staging: lane covers LDS line (row = base + lane>>3, slot = lane&7);
    // global source slot pre-swizzled: slot' = (lane&7) ^ (row&7), row&7 == lane>>3.
    const int srcslot = (lane & 7) ^ ((lane >> 3) & 7);
    const unsigned short* aSt = Az + (size_t)(bm + wave * 16 + (lane >> 3)) * Kd + srcslot * 8;
    const unsigned short* bSt = Bz + (size_t)(bn + wave * 16 + (lane >> 3)) * Kd + srcslot * 8;
    unsigned short* aLd0 = A0 + wave * 16 * 64;
    unsigned short* bLd0 = B0 + wave * 16 * 64;
    unsigned short* aLd1 = A1 + wave * 16 * 64;
    unsigned short* bLd1 = B1 + wave * 16 * 64;

    // stage half h (128 rows) of K-tile t: 2 x gl2lds16 (8 rows x 64k = 1KB each)
#define STG(gbase, ld, t, h) { \
    gl2lds16((gbase) + (h) * 128 * Kd + (t) * 64,          (ld) + (h) * 128 * 64); \
    gl2lds16((gbase) + (h) * 128 * Kd + 8 * Kd + (t) * 64, (ld) + (h) * 128 * 64 + 8 * 64); }

    f32x4 acc[2][2][4][2] = {};
    bf16x8 af[4][2], bf0[2][2], bf1[2][2];

#define LD_AF(Abuf, HM) { _Pragma("unroll") for (int m = 0; m < 4; ++m) { \
      const int row_ = (HM) * 128 + r2 * 64 + m * 16 + lm; \
      const char* rp_ = (const char*)(Abuf) + row_ * 128; \
      const int sw_ = (row_ & 7) << 4; \
      af[m][0] = *(const bf16x8*)(rp_ + ((quad * 16) ^ sw_)); \
      af[m][1] = *(const bf16x8*)(rp_ + ((64 + quad * 16) ^ sw_)); } }

#define LD_BF(dst, Bbuf, HN) { _Pragma("unroll") for (int n = 0; n < 2; ++n) { \
      const int row_ = (HN) * 128 + c4 * 32 + n * 16 + lm; \
      const char* rp_ = (const char*)(Bbuf) + row_ * 128; \
      const int sw_ = (row_ & 7) << 4; \
      dst[n][0] = *(const bf16x8*)(rp_ + ((quad * 16) ^ sw_)); \
      dst[n][1] = *(const bf16x8*)(rp_ + ((64 + quad * 16) ^ sw_)); } }

#define MM(HM, HN, BF) { _Pragma("unroll") for (int m = 0; m < 4; ++m) \
      _Pragma("unroll") for (int n = 0; n < 2; ++n) \
      _Pragma("unroll") for (int ks = 0; ks < 2; ++ks) \
        acc[HM][HN][m][n] = __builtin_amdgcn_mfma_f32_16x16x32_bf16(af[m][ks], BF[n][ks], acc[HM][HN][m][n], 0, 0, 0); }

#define BAR_MFMA(HM, HN, BF) \
    __builtin_amdgcn_s_barrier(); \
    asm volatile("s_waitcnt lgkmcnt(0)" ::: "memory"); \
    __builtin_amdgcn_sched_barrier(0); \
    __builtin_amdgcn_s_setprio(1); \
    MM(HM, HN, BF); \
    __builtin_amdgcn_s_setprio(0);

    // prologue: tile0 full + tile1 h0 halves (12 loads/wave); drain the 8 oldest (=t0)
    STG(aSt, aLd0, 0, 0); STG(aSt, aLd0, 0, 1);
    STG(bSt, bLd0, 0, 0); STG(bSt, bLd0, 0, 1);
    STG(aSt, aLd1, 1, 0);
    STG(bSt, bLd1, 1, 0);
    asm volatile("s_waitcnt vmcnt(4)" ::: "memory");
    __builtin_amdgcn_s_barrier();

    #pragma unroll
    for (int i = 0; i < 4; ++i) {   // 2 K-tiles per iter, 8 K-tiles total (K=512)
        const int t1 = 2 * i + 1, t2 = 2 * i + 2, t3 = 2 * i + 3;
        // p0: (hm0,hn0) buf0 | stage t1 h1 halves -> buf1 (regions last read prev p5/p6)
        LD_AF(A0, 0); LD_BF(bf0, B0, 0);
        STG(aSt, aLd1, t1, 1); STG(bSt, bLd1, t1, 1);
        BAR_MFMA(0, 0, bf0);
        __builtin_amdgcn_s_barrier();
        // p1: (hm0,hn1) buf0 (af reused, bf1 new)
        LD_BF(bf1, B0, 1);
        BAR_MFMA(0, 1, bf1);
        __builtin_amdgcn_s_barrier();
        // p2: (hm1,hn0) buf0 | stage t2 A.h0 (last read p0)
        LD_AF(A0, 1);
        if (t2 < 8) STG(aSt, aLd0, t2, 0);
        BAR_MFMA(1, 0, bf0);
        __builtin_amdgcn_s_barrier();
        // p3: (hm1,hn1) buf0 | stage t2 B.h0 (last read p0) | counted vmcnt
        if (t2 < 8) STG(bSt, bLd0, t2, 0);
        BAR_MFMA(1, 1, bf1);
        if (i == 3) { asm volatile("s_waitcnt vmcnt(0)" ::: "memory"); }  // tail: t7.h1 must land
        else        { asm volatile("s_waitcnt vmcnt(4)" ::: "memory"); }  // buf1 tile landed
        __builtin_amdgcn_s_barrier();
        // p4: (hm0,hn0) buf1 | stage t2 h1 halves -> buf0 (A.h1 last read p2, B.h1 p1)
        LD_AF(A1, 0); LD_BF(bf0, B1, 0);
        if (t2 < 8) { STG(aSt, aLd0, t2, 1); STG(bSt, bLd0, t2, 1); }
        BAR_MFMA(0, 0, bf0);
        __builtin_amdgcn_s_barrier();
        // p5: (hm0,hn1) buf1
        LD_BF(bf1, B1, 1);
        BAR_MFMA(0, 1, bf1);
        __builtin_amdgcn_s_barrier();
        // p6: (hm1,hn0) buf1 | stage t3 A.h0 (last read p4)
        LD_AF(A1, 1);
        if (t3 < 8) STG(aSt, aLd1, t3, 0);
        BAR_MFMA(1, 0, bf0);
        __builtin_amdgcn_s_barrier();
        // p7: (hm1,hn1) buf1 | stage t3 B.h0 (last read p4) | counted vmcnt
        if (t3 < 8) STG(bSt, bLd1, t3, 0);
        BAR_MFMA(1, 1, bf1);
        asm volatile("s_waitcnt vmcnt(4)" ::: "memory");   // buf0 tile t2 landed
        __builtin_amdgcn_s_barrier();
    }

    // ---- epilogue: exp + rowsum, swizzled LDS restage, coalesced store ----
    asm volatile("" ::: "memory");
    unsigned short* Ct = (unsigned short*)smem8;          // [256] rows x 512 B, same XOR swizzle
    float* lr = lrow + (size_t)z * 4096;
    unsigned short* Cz = Pb + (size_t)z * (size_t)N * N;

    #pragma unroll
    for (int hm = 0; hm < 2; ++hm)
    #pragma unroll
    for (int m = 0; m < 4; ++m)
    #pragma unroll
    for (int i2 = 0; i2 < 4; ++i2) {
        const int row = hm * 128 + r2 * 64 + m * 16 + quad * 4 + i2;  // C/D: row=quad*4+reg
        char* rowp = (char*)Ct + row * 512;
        const int sw = (row & 7) << 4;
        float rs = 0.f;
        #pragma unroll
        for (int hn = 0; hn < 2; ++hn)
        #pragma unroll
        for (int n = 0; n < 2; ++n) {
            const float p = __expf(acc[hm][hn][m][n][i2] * scale);
            rs += p;
            const int col = hn * 128 + c4 * 32 + n * 16 + lm;         // C/D: col=lm
            *(unsigned short*)(rowp + ((col * 2) ^ sw)) = f2bf(p);
        }
        rs += __shfl_xor(rs, 1);
        rs += __shfl_xor(rs, 2);
        rs += __shfl_xor(rs, 4);
        rs += __shfl_xor(rs, 8);
        if (lm == 0) atomicAdd(lr + bm + row, rs);
    }
    asm volatile("s_waitcnt lgkmcnt(0)" ::: "memory");
    __builtin_amdgcn_s_barrier();
    __builtin_amdgcn_sched_barrier(0);
    #pragma unroll
    for (int j = 0; j < 16; ++j) {                        // 256 rows x 512 B out
        const int row = j * 16 + (tid >> 5);
        const int cg  = tid & 31;
        const uint4 v = *(const uint4*)((const char*)Ct + row * 512 + ((cg * 16) ^ ((row & 7) << 4)));
        *(uint4*)(Cz + (size_t)(bm + row) * N + bn + cg * 8) = v;
    }
#undef STG
#undef LD_AF
#undef LD_BF
#undef MM
#undef BAR_MFMA
}

// ---------- launch ----------
extern "C" void kernel_launch(void* const* d_in, const int* in_sizes, int n_in,
                              void* d_out, int out_size, void* d_ws, size_t ws_size,
                              hipStream_t stream) {
    const float* x  = (const float*)d_in[0];
    const float* rp = (const float*)d_in[1];
    const float* Wq = (const float*)d_in[2];
    const float* bq = (const float*)d_in[3];
    const float* Wk = (const float*)d_in[4];
    const float* bk = (const float*)d_in[5];
    const float* Wv = (const float*)d_in[6];
    const float* bv = (const float*)d_in[7];

    char* ws = (char*)d_ws;
    unsigned short* xb  = (unsigned short*)(ws + OFF_XB);
    unsigned short* sb  = (unsigned short*)(ws + OFF_SB);
    unsigned short* wqb = (unsigned short*)(ws + OFF_WQB);
    unsigned short* wkb = (unsigned short*)(ws + OFF_WKB);
    unsigned short* wvb = (unsigned short*)(ws + OFF_WVB);
    float*          bqk = (float*)(ws + OFF_BQK);
    unsigned short* qb  = (unsigned short*)(ws + OFF_QB);
    unsigned short* k2b = (unsigned short*)(ws + OFF_K2B);
    unsigned short* vtb = (unsigned short*)(ws + OFF_VTB);
    unsigned short* pb  = (unsigned short*)(ws + OFF_PB);
    float*          lrow = (float*)(ws + OFF_L);

    // 1. casts + x+rp fusion + bias prep + lrow zero
    prep_all<<<8448, 256, 0, stream>>>(x, rp, Wq, Wk, Wv, bq, bk,
                                       xb, sb, wqb, wkb, wvb, bqk, lrow);

    // 2+3. fused via z: z=0 -> Q = x@Wq^T + bq ; z=1 -> K2 = (x+rp)@Wk^T + 2bk
    gemm_bt<0, 1, 2><<<dim3(4, 128, 2), 256, 0, stream>>>(
        xb, wqb, qb, 16384, 512, 512,
        8388608, 262144, 8388608,
        bqk, 512, nullptr, 1.0f, nullptr, 0);
    // 4. V^T[b][d][k] = sum_h Wv[d,h] x[b,k,h] + bv[d]
    gemm_bt<0, 0, 2><<<dim3(32, 4, 4), 256, 0, stream>>>(
        wvb, xb, vtb, 512, 4096, 512,
        0, (long long)S * H, (long long)S * H,
        nullptr, 0, bv, 1.0f, nullptr, 0);
    // 5. P = exp(Q@K2^T / sqrt(512)); lrow += row sums  — 8-phase 256^2 kernel
    qk_exp_8ph<<<dim3(16, 16, 4), 512, 0, stream>>>(qb, k2b, pb, lrow);
    // 6. O = (P @ V) / l   (per-batch: M=4096, N=512, K=4096), BK=128 (4 panels)
    gemm_bt<1, 1, 4><<<dim3(4, 32, 4), 256, 0, stream>>>(
        pb, vtb, d_out, 4096, 512, 4096,
        (long long)S * S, (long long)S * H, (long long)S * H,
        nullptr, 0, nullptr, 1.0f, lrow, 4096);
}